// Round 6
// baseline (844.636 us; speedup 1.0000x reference)
//
#include <hip/hip_runtime.h>
#include <cfloat>
#include <cmath>

// NoisyTopKRouter eval-mode: logits = x @ W^T, top-2 + softmax over top-2.
// N=131072, D=2048, E=16. Outputs (concatenated flat in d_out as float32):
//   [0 .. 2N)   topk indices (as float values; ref dtype int64)
//   [2N .. 4N)  gating weights (softmax over the two top logits)
//
// Barrier-free wave-private pipeline:
//   - x staged global->LDS via global_load_lds (zero-VGPR, 1 KB/instr,
//     4 rows x 64 floats per instruction), double-buffered per wave.
//   - Slabs are wave-private -> NO __syncthreads anywhere; synchronization is
//     per-wave counted s_waitcnt vmcnt(N):
//       issue order per phase: W(p) x16 | fence | stage(p+1) x4 | vmcnt(20)
//       -> stage(p) complete (W(p)+stage(p+1)=20 in flight); compiler's own
//       wait before first W use resolves to vmcnt(4). Last phase: vmcnt(16).
//   - LDS layout: KPAD=260 pad per k-block; 16-lane-broadcast reads across 4
//     distinct bank-quads = conflict-free (measured 0 conflicts in round 5).
// W read per-lane from global (L1/L2-hot), 16 float4 per phase.
// Accumulation order identical to rounds 1-5 (absmax 0.0).

constexpr int D = 2048;
constexpr int E = 16;
constexpr int BLOCK = 256;          // 4 waves
constexpr int RB = 64;              // rows per block (16 per wave)
constexpr int PW = 64;              // phase width (floats of D)
constexpr int NP = D / PW;          // 32 phases
constexpr int KPAD = 260;           // 256 floats per k-block + 4 pad
constexpr int WSLAB = 4 * KPAD;     // 1040 floats per wave per buffer
constexpr int SLAB = 4 * WSLAB;     // 4160 floats per buffer (4 waves)

__global__ __launch_bounds__(BLOCK, 2) void router_kernel(
    const float* __restrict__ x, const float* __restrict__ W,
    float* __restrict__ out, int N) {
  __shared__ float xs[2][SLAB];     // 2 x 16640 B -> 4 blocks/CU

  const int tid  = threadIdx.x;
  const int lane = tid & 63;
  const int wid  = tid >> 6;        // 0..3
  const int e    = lane & 15;       // expert owned by this lane
  const int q    = lane >> 4;       // lane sub-group 0..3
  const int waverow = blockIdx.x * RB + wid * 16;
  if (waverow >= N) return;

  // staging: instr k, lane l -> global row (waverow + 4k + q), col p*64 + 4e
  // LDS dest: wave-uniform base + lane*16 B  (= k*KPAD + (q*16+e)*4 floats)
  const float* gbase = x + (size_t)(waverow + q) * D + e * 4;
  float* lwave = &xs[0][wid * WSLAB];                  // wave-uniform
  const float* rbase = &xs[0][wid * WSLAB + q * KPAD]; // this lane's read base
  const float* wbase = W + e * D;

  auto stage = [&](int p, int buf) {
    const float* g = gbase + p * PW;
    float* ld = lwave + buf * SLAB;
    #pragma unroll
    for (int k = 0; k < 4; ++k)
      __builtin_amdgcn_global_load_lds(
          (const __attribute__((address_space(1))) void*)(g + (size_t)(4 * k) * D),
          (__attribute__((address_space(3))) void*)(ld + k * KPAD), 16, 0, 0);
  };

  float4 acc[4];
  #pragma unroll
  for (int r = 0; r < 4; ++r) acc[r] = make_float4(0.f, 0.f, 0.f, 0.f);

  // prologue: stage phase 0 into buffer 0
  stage(0, 0);

  #pragma unroll 1
  for (int p = 0; p < NP - 1; ++p) {
    const int cur = p & 1;
    // W chunk for phase p (16 float4; issued before the stage so the
    // compiler's auto-wait for W resolves to vmcnt(4), not vmcnt(0))
    const float* wp = wbase + p * PW;
    float4 wv[16];
    #pragma unroll
    for (int j = 0; j < 16; ++j)
      wv[j] = *reinterpret_cast<const float4*>(wp + 4 * j);
    // pin issue order: W loads above, stage below
    asm volatile("" ::: "memory");
    stage(p + 1, cur ^ 1);
    // wait for stage(p): W(p)16 + stage(p+1)4 = 20 may remain in flight
    asm volatile("s_waitcnt vmcnt(20)" ::: "memory");
    __builtin_amdgcn_sched_barrier(0);
    // compute phase p from buf[cur]
    const float* ls = rbase + cur * SLAB;
    #pragma unroll
    for (int j = 0; j < 16; ++j) {
      #pragma unroll
      for (int r = 0; r < 4; ++r) {
        const float4 xv = *reinterpret_cast<const float4*>(ls + r * 64 + 4 * j);
        acc[r].x = fmaf(xv.x, wv[j].x, acc[r].x);
        acc[r].y = fmaf(xv.y, wv[j].y, acc[r].y);
        acc[r].z = fmaf(xv.z, wv[j].z, acc[r].z);
        acc[r].w = fmaf(xv.w, wv[j].w, acc[r].w);
      }
    }
  }

  // final phase NP-1 (no stage; only W(NP-1)=16 may remain in flight)
  {
    const int p = NP - 1;
    const int cur = p & 1;
    const float* wp = wbase + p * PW;
    float4 wv[16];
    #pragma unroll
    for (int j = 0; j < 16; ++j)
      wv[j] = *reinterpret_cast<const float4*>(wp + 4 * j);
    asm volatile("s_waitcnt vmcnt(16)" ::: "memory");
    __builtin_amdgcn_sched_barrier(0);
    const float* ls = rbase + cur * SLAB;
    #pragma unroll
    for (int j = 0; j < 16; ++j) {
      #pragma unroll
      for (int r = 0; r < 4; ++r) {
        const float4 xv = *reinterpret_cast<const float4*>(ls + r * 64 + 4 * j);
        acc[r].x = fmaf(xv.x, wv[j].x, acc[r].x);
        acc[r].y = fmaf(xv.y, wv[j].y, acc[r].y);
        acc[r].z = fmaf(xv.z, wv[j].z, acc[r].z);
        acc[r].w = fmaf(xv.w, wv[j].w, acc[r].w);
      }
    }
  }

  float s_i1 = 0.f, s_i2 = 0.f, s_g1 = 0.f, s_g2 = 0.f;

  #pragma unroll
  for (int r = 0; r < 4; ++r) {
    // pairwise horizontal sum (same order as rounds 1-5, absmax was 0.0)
    float m1 = (acc[r].x + acc[r].y) + (acc[r].z + acc[r].w);
    int   i1 = e;
    float m2 = -FLT_MAX;
    int   i2 = E;
    // top-2 butterfly across the 16 expert lanes; lowest index wins ties
    #pragma unroll
    for (int mask = 1; mask < 16; mask <<= 1) {
      const float om1 = __shfl_xor(m1, mask);
      const int   oi1 = __shfl_xor(i1, mask);
      const float om2 = __shfl_xor(m2, mask);
      const int   oi2 = __shfl_xor(i2, mask);
      const bool bwin = (om1 > m1) || (om1 == m1 && oi1 < i1);
      const float a1 = bwin ? om1 : m1; const int ai1 = bwin ? oi1 : i1;
      const float l1 = bwin ? m1 : om1; const int li1 = bwin ? i1 : oi1;
      const float a2 = bwin ? om2 : m2; const int ai2 = bwin ? oi2 : i2;
      const bool lwin = (l1 > a2) || (l1 == a2 && li1 < ai2);
      m1 = a1; i1 = ai1;
      m2 = lwin ? l1 : a2; i2 = lwin ? li1 : ai2;
    }
    if (e == r) {   // lane r keeps row (q*4+r)'s result for the store below
      const float ex  = expf(m2 - m1);        // m2 <= m1 -> ex in (0,1]
      const float inv = 1.0f / (1.0f + ex);
      s_i1 = (float)i1; s_i2 = (float)i2;
      s_g1 = inv;       s_g2 = ex * inv;
    }
  }

  if (e < 4) {
    const int row = waverow + q * 4 + e;
    float2* outi = reinterpret_cast<float2*>(out);
    outi[row] = make_float2(s_i1, s_i2);
    float2* outw = reinterpret_cast<float2*>(out + (size_t)N * 2);
    outw[row] = make_float2(s_g1, s_g2);
  }
}

extern "C" void kernel_launch(void* const* d_in, const int* in_sizes, int n_in,
                              void* d_out, int out_size, void* d_ws, size_t ws_size,
                              hipStream_t stream) {
  const float* x = (const float*)d_in[0];
  const float* W = (const float*)d_in[1];
  float* out = (float*)d_out;
  const int N = in_sizes[0] / D;       // 131072
  const int grid = (N + RB - 1) / RB;  // 2048
  router_kernel<<<grid, BLOCK, 0, stream>>>(x, W, out, N);
}

// Round 8
// 357.566 us; speedup vs baseline: 2.3622x; 2.3622x over previous
//
#include <hip/hip_runtime.h>
#include <cfloat>
#include <cmath>

// NoisyTopKRouter eval-mode: logits = x @ W^T, top-2 + softmax over top-2.
// N=131072, D=2048, E=16. Outputs (concatenated flat in d_out as float32):
//   [0 .. 2N)   topk indices (as float values; ref dtype int64)
//   [2N .. 4N)  gating weights (softmax over the two top logits)
//
// BIT-EXACTNESS CONSTRAINT (learned round 7): each (row, expert) dot must be
// computed by ONE lane over all of D with 4 mod-4 fma chains, d ascending,
// reduced as (c0+c1)+(c2+c3). This order matched np absmax 0.0 in rounds 1-6;
// a lane-sliced tree sum flipped near-tie argmaxes (absmax 12).
//
// Mapping: lane = (ep = lane>>3: expert-pair, rp = lane&7: row-pair).
// Lane computes experts {2ep,2ep+1} x rows {2rp,2rp+1} -> DS traffic halved
// vs lane=expert (round 5), W loads L1-hot broadcast. All pipes < HBM floor.
//
// x staged global->LDS via global_load_lds (zero-VGPR, 1 KB/instr), PW=128
// double-buffered, one __syncthreads per phase (16 total). LDS layout:
// per wave 8 blocks of [2 rows x 32 f4] + 1 f4 pad (65 f4) -> stage-linear,
// read bank-quads (rp + j) % 8 = all 8 distinct, 8-way broadcast: conflict-free.

constexpr int D = 2048;
constexpr int E = 16;
constexpr int BLOCK = 256;            // 4 waves
constexpr int RB = 64;                // rows per block (16 per wave)
constexpr int PW = 128;               // phase width (floats of D)
constexpr int NP = D / PW;            // 16 phases
constexpr int BLKF4 = 65;             // 2 rows x 32 f4 + 1 pad f4
constexpr int WSLABF = 8 * BLKF4 * 4; // 2080 floats per wave per buffer
constexpr int SLABF = 4 * WSLABF;     // 8320 floats per block buffer

__global__ __launch_bounds__(BLOCK, 2) void router_kernel(
    const float* __restrict__ x, const float* __restrict__ W,
    float* __restrict__ out, int N) {
  __shared__ float xs[2][SLABF];      // 2 x 33280 B -> 2 blocks/CU

  const int tid  = threadIdx.x;
  const int lane = tid & 63;
  const int wid  = tid >> 6;          // 0..3
  const int ep   = lane >> 3;         // expert-pair 0..7 -> experts 2ep, 2ep+1
  const int rp   = lane & 7;          // row-pair 0..7 -> rows 2rp, 2rp+1
  const int waverow = blockIdx.x * RB + wid * 16;
  if (waverow >= N) return;

  // staging: instr k stages rows {2k, 2k+1} x 32 f4 (two 512 B segments).
  // lane covers row 2k + (lane>>5), float col (lane&31)*4 of the phase slice.
  const float* gbase = x + (size_t)(waverow + (lane >> 5)) * D + (lane & 31) * 4;
  float* lwave = &xs[0][wid * WSLABF];                     // wave-uniform base
  // read base for this lane's rows (block rp): f4 rp*65 (+32 for second row)
  const float* rbase = &xs[0][wid * WSLABF + rp * BLKF4 * 4];
  const float* wb0 = W + (size_t)(2 * ep) * D;
  const float* wb1 = wb0 + D;

  auto stage = [&](int p, int buf) {
    const float* g = gbase + p * PW;
    float* ld = lwave + buf * SLABF;
    #pragma unroll
    for (int k = 0; k < 8; ++k)
      __builtin_amdgcn_global_load_lds(
          (const __attribute__((address_space(1))) void*)(g + (size_t)(2 * k) * D),
          (__attribute__((address_space(3))) void*)(ld + k * BLKF4 * 4), 16, 0, 0);
  };

  // acc[r][e] = float4 of mod-4 chains for row 2rp+r, expert 2ep+e
  float4 a00 = make_float4(0.f, 0.f, 0.f, 0.f), a01 = a00, a10 = a00, a11 = a00;

  stage(0, 0);
  __syncthreads();

  for (int p = 0; p < NP; ++p) {
    const int cur = p & 1;
    if (p + 1 < NP) stage(p + 1, cur ^ 1);   // flies under this phase's compute
    const float* ls = rbase + cur * SLABF;
    const float* w0 = wb0 + p * PW;
    const float* w1 = wb1 + p * PW;
    #pragma unroll 4
    for (int j = 0; j < PW / 4; ++j) {       // 32 j-steps
      const float4 xv0 = *reinterpret_cast<const float4*>(ls + 4 * j);        // row 2rp
      const float4 xv1 = *reinterpret_cast<const float4*>(ls + 128 + 4 * j);  // row 2rp+1
      const float4 wv0 = *reinterpret_cast<const float4*>(w0 + 4 * j);        // expert 2ep
      const float4 wv1 = *reinterpret_cast<const float4*>(w1 + 4 * j);        // expert 2ep+1
      a00.x = fmaf(xv0.x, wv0.x, a00.x); a00.y = fmaf(xv0.y, wv0.y, a00.y);
      a00.z = fmaf(xv0.z, wv0.z, a00.z); a00.w = fmaf(xv0.w, wv0.w, a00.w);
      a01.x = fmaf(xv0.x, wv1.x, a01.x); a01.y = fmaf(xv0.y, wv1.y, a01.y);
      a01.z = fmaf(xv0.z, wv1.z, a01.z); a01.w = fmaf(xv0.w, wv1.w, a01.w);
      a10.x = fmaf(xv1.x, wv0.x, a10.x); a10.y = fmaf(xv1.y, wv0.y, a10.y);
      a10.z = fmaf(xv1.z, wv0.z, a10.z); a10.w = fmaf(xv1.w, wv0.w, a10.w);
      a11.x = fmaf(xv1.x, wv1.x, a11.x); a11.y = fmaf(xv1.y, wv1.y, a11.y);
      a11.z = fmaf(xv1.z, wv1.z, a11.z); a11.w = fmaf(xv1.w, wv1.w, a11.w);
    }
    __syncthreads();   // staged buffer landed + all reads of ls complete
  }

  // ---- epilogue: per row, top-2 over 16 experts + 2-way softmax ----
  float res_i1[2], res_i2[2], res_g1[2], res_g2[2];
  #pragma unroll
  for (int r = 0; r < 2; ++r) {
    // horizontal sums in the proven order
    const float4 ae0 = r ? a10 : a00;
    const float4 ae1 = r ? a11 : a01;
    const float v0 = (ae0.x + ae0.y) + (ae0.z + ae0.w);  // expert 2ep
    const float v1 = (ae1.x + ae1.y) + (ae1.z + ae1.w);  // expert 2ep+1
    // local top-2 of the lane's two experts (tie -> lower index first)
    const bool win = v1 > v0;
    float m1 = win ? v1 : v0;  int i1 = win ? 2 * ep + 1 : 2 * ep;
    float m2 = win ? v0 : v1;  int i2 = win ? 2 * ep : 2 * ep + 1;
    // butterfly merge across the 8 ep-lanes (lane bits 3..5); selection is
    // rounding-free, tie-break = lowest index (matches jax.lax.top_k)
    #pragma unroll
    for (int mask = 8; mask < 64; mask <<= 1) {
      const float om1 = __shfl_xor(m1, mask);
      const int   oi1 = __shfl_xor(i1, mask);
      const float om2 = __shfl_xor(m2, mask);
      const int   oi2 = __shfl_xor(i2, mask);
      const bool bwin = (om1 > m1) || (om1 == m1 && oi1 < i1);
      const float b1 = bwin ? om1 : m1; const int bi1 = bwin ? oi1 : i1;
      const float l1 = bwin ? m1 : om1; const int li1 = bwin ? i1 : oi1;
      const float b2 = bwin ? om2 : m2; const int bi2 = bwin ? oi2 : i2;
      const bool lwin = (l1 > b2) || (l1 == b2 && li1 < bi2);
      m1 = b1; i1 = bi1;
      m2 = lwin ? l1 : b2; i2 = lwin ? li1 : bi2;
    }
    const float ex  = expf(m2 - m1);      // m2 <= m1 -> ex in (0,1]
    const float inv = 1.0f / (1.0f + ex);
    res_i1[r] = (float)i1; res_i2[r] = (float)i2;
    res_g1[r] = inv;       res_g2[r] = ex * inv;
  }

  if (ep == 0) {   // 8 writer lanes per wave, each owns rows 2rp, 2rp+1
    const int row = waverow + 2 * rp;
    *reinterpret_cast<float4*>(out + (size_t)row * 2) =
        make_float4(res_i1[0], res_i2[0], res_i1[1], res_i2[1]);
    *reinterpret_cast<float4*>(out + (size_t)N * 2 + (size_t)row * 2) =
        make_float4(res_g1[0], res_g2[0], res_g1[1], res_g2[1]);
  }
}

extern "C" void kernel_launch(void* const* d_in, const int* in_sizes, int n_in,
                              void* d_out, int out_size, void* d_ws, size_t ws_size,
                              hipStream_t stream) {
  const float* x = (const float*)d_in[0];
  const float* W = (const float*)d_in[1];
  float* out = (float*)d_out;
  const int N = in_sizes[0] / D;       // 131072
  const int grid = (N + RB - 1) / RB;  // 2048
  router_kernel<<<grid, BLOCK, 0, stream>>>(x, W, out, N);
}